// Round 10
// baseline (316.921 us; speedup 1.0000x reference)
//
#include <hip/hip_runtime.h>
#include <hip/hip_bf16.h>
#include <hip/hip_fp8.h>

typedef float f32x4 __attribute__((ext_vector_type(4)));
typedef int   i32x4 __attribute__((ext_vector_type(4)));
typedef int   i32x8 __attribute__((ext_vector_type(8)));

#define N_SPK 1024
#define M_UTT 40
#define D_FEAT 768
#define NROWS (N_SPK * M_UTT)
#define LOG2E 1.44269504088896340736f
#define LN2   0.69314718055994530942f

#define BM 128
#define BN 128
#define BKB 128            // fp8 elems (=bytes) per K-tile (one MX MFMA K-window)
#define KT (D_FEAT / BKB)  // 6
#define ROWB 768           // bytes per fp8 source row

// xn stored *8, cc stored *8, scales = 1.0  ->  acc = 64 * sim
#define INV_SS (1.0f / 64.0f)
#define SCL 8.0f
#define SCALE1 0x7F7F7F7F  // e8m0 127 = 2^0 in all 4 bytes

__device__ __forceinline__ unsigned char to_fp8(float v) {
  __hip_fp8_e4m3 t(v);
  return (unsigned char)t.__x;
}

// ---------------- Kernel 1: fused L2-normalize + inclusive centroid (fp8, x8) ----------------
__global__ __launch_bounds__(256) void k_norm_cent(const float* __restrict__ x,
                                                   unsigned char* __restrict__ xn,
                                                   unsigned char* __restrict__ cc) {
  const int n = blockIdx.x, t = threadIdx.x;
  const float* xb = x + (size_t)n * (M_UTT * D_FEAT);
  unsigned char* ob = xn + (size_t)n * (M_UTT * D_FEAT);
  const int lane = t & 63, wv = t >> 6;
  __shared__ float wsum[2][2][4];  // [parity][row-in-pair][wave]
  float c0 = 0.f, c1 = 0.f, c2 = 0.f;
  for (int m = 0; m < M_UTT; m += 2) {
    const int p = (m >> 1) & 1;
    const float* r0 = xb + (size_t)m * D_FEAT;
    const float* r1 = r0 + D_FEAT;
    float a0 = r0[t], a1 = r0[t + 256], a2 = r0[t + 512];
    float b0 = r1[t], b1 = r1[t + 256], b2 = r1[t + 512];
    float sq0 = a0 * a0 + a1 * a1 + a2 * a2;
    float sq1 = b0 * b0 + b1 * b1 + b2 * b2;
#pragma unroll
    for (int d = 1; d < 64; d <<= 1) {
      sq0 += __shfl_xor(sq0, d, 64);
      sq1 += __shfl_xor(sq1, d, 64);
    }
    if (lane == 0) { wsum[p][0][wv] = sq0; wsum[p][1][wv] = sq1; }
    __syncthreads();  // parity double-buffer: slot p reused 2 barriers later -> safe
    const float t0 = wsum[p][0][0] + wsum[p][0][1] + wsum[p][0][2] + wsum[p][0][3];
    const float t1 = wsum[p][1][0] + wsum[p][1][1] + wsum[p][1][2] + wsum[p][1][3];
    const float i0 = 1.0f / fmaxf(sqrtf(t0), 1e-12f);
    const float i1 = 1.0f / fmaxf(sqrtf(t1), 1e-12f);
    a0 *= i0; a1 *= i0; a2 *= i0;
    b0 *= i1; b1 *= i1; b2 *= i1;
    unsigned char* o0 = ob + (size_t)m * D_FEAT;
    unsigned char* o1 = o0 + D_FEAT;
    o0[t] = to_fp8(a0 * SCL); o0[t + 256] = to_fp8(a1 * SCL); o0[t + 512] = to_fp8(a2 * SCL);
    o1[t] = to_fp8(b0 * SCL); o1[t + 256] = to_fp8(b1 * SCL); o1[t + 512] = to_fp8(b2 * SCL);
    c0 += a0 + b0; c1 += a1 + b1; c2 += a2 + b2;
  }
  unsigned char* co = cc + (size_t)n * D_FEAT;
  co[t]       = to_fp8(c0 * (SCL / M_UTT));
  co[t + 256] = to_fp8(c1 * (SCL / M_UTT));
  co[t + 512] = to_fp8(c2 * (SCL / M_UTT));
}

// ---------------- Kernel 2: 128x128 MX-fp8 GEMM, K=128/tile, 6 iters, 2 blocks/CU ----------------
// 256 thr = 4 waves (2x2 of 64x64; 4x4 frags of mfma_scale 16x16x128; 16 MFMA/K-tile).
// All scales = 1.0 (0x7F e8m0) so the scale lane-layout is irrelevant (pure 2x-rate fp8).
// LDS 64KB dbuf (32KB/tile: A 16KB + B 16KB). Row = 128B = full K-window; 16B unit u of
// row r stored at physical slot u ^ (r&7) (XOR involution; GLD dest stays linear with
// pre-swizzled SOURCE column; reads use the same XOR -> <=2-way conflicts, free).
// Lane (l16,lg) operand = k-bytes [lg*32, lg*32+32) of its row: two ds_read_b128 at
// slot (2lg)^(r&7) and that ^1 (addr ^ 16).
// Loop: stage k+1 (8 GLD) -> vmcnt(8) -> barrier -> 16 reads + 16 MFMA -> lgkmcnt(0) -> barrier.
#define GLD(g, l) __builtin_amdgcn_global_load_lds( \
    (const __attribute__((address_space(1))) unsigned int*)(g), \
    (__attribute__((address_space(3))) unsigned int*)(l), 16, 0, 0)

__global__ __launch_bounds__(256, 2) void k_gemm_part(
    const unsigned char* __restrict__ XN, const unsigned char* __restrict__ CC,
    const float* __restrict__ wp, const float* __restrict__ bp,
    float2* __restrict__ ppart, float* __restrict__ picked2) {

  __shared__ __align__(16) char smem[65536];

  const int tid  = threadIdx.x;
  const int wave = tid >> 6, lane = tid & 63;
  const int l16  = lane & 15, lg = lane >> 4;
  const int wr   = wave >> 1, wc = wave & 1;

  // XCD swizzle: 2560 = 8 XCD x 320; a row-tile's 8 col-blocks share one XCD's L2
  const int bid = blockIdx.x;
  const int xcd = bid & 7;
  const int tt  = bid >> 3;              // 0..319
  const int rb  = xcd * 40 + (tt >> 3);  // 0..319
  const int cb  = tt & 7;                // 0..7
  const int rowbase = rb * BM;
  const int colbase = cb * BN;

  // staging: thread t writes LDS linear bytes q*4096 + t*16 -> row R = q*32 + (t>>3),
  // phys slot p = t&7 holds logical unit u = p ^ (R&7) = (t&7) ^ ((t>>3)&7).
  const int row0 = tid >> 3;                       // 0..31 (chunk q adds 32)
  const int u    = (tid & 7) ^ ((tid >> 3) & 7);   // logical 16B unit to fetch
  const int t16  = tid * 16;
  const unsigned char* gA = XN + (size_t)(rowbase + row0) * ROWB + u * 16;
  const unsigned char* gB = CC + (size_t)(colbase + row0) * ROWB + u * 16;

  // fragment read offsets: frag row r = band*64 + i*16 + l16; r&7 = l16&7.
  // lo-read addr = r*128 + (((2*lg) ^ (l16&7)) << 4); hi-read = lo ^ 16.
  const int m7 = l16 & 7;
  const int s0 = ((2 * lg) ^ m7) << 4;
  int aoff[4], boff[4];
#pragma unroll
  for (int i = 0; i < 4; ++i) {
    aoff[i] = (wr * 64 + i * 16 + l16) * 128 + s0;
    boff[i] = 16384 + (wc * 64 + i * 16 + l16) * 128 + s0;
  }

  f32x4 acc[4][4];
#pragma unroll
  for (int i = 0; i < 4; ++i)
#pragma unroll
    for (int jj = 0; jj < 4; ++jj) acc[i][jj] = (f32x4){0.f, 0.f, 0.f, 0.f};

  auto STAGE = [&](int buf, int koff) {
    char* sb = smem + buf * 32768;
#pragma unroll
    for (int q = 0; q < 4; ++q)
      GLD(gA + (size_t)q * (32 * ROWB) + koff, sb + q * 4096 + t16);
#pragma unroll
    for (int q = 0; q < 4; ++q)
      GLD(gB + (size_t)q * (32 * ROWB) + koff, sb + 16384 + q * 4096 + t16);
  };

  STAGE(0, 0);  // prologue: tile 0

  for (int k = 0; k < KT; ++k) {
    const char* bb = smem + (k & 1) * 32768;
    if (k + 1 < KT) {
      STAGE((k + 1) & 1, (k + 1) * BKB);
      asm volatile("s_waitcnt vmcnt(8)" ::: "memory");  // tile k landed; k+1 in flight
    } else {
      asm volatile("s_waitcnt vmcnt(0)" ::: "memory");
    }
    __builtin_amdgcn_s_barrier();

    i32x8 av[4], bv[4];
#pragma unroll
    for (int i = 0; i < 4; ++i) {
      const i32x4 lo = *(const i32x4*)(bb + aoff[i]);
      const i32x4 hi = *(const i32x4*)(bb + (aoff[i] ^ 16));
      av[i] = __builtin_shufflevector(lo, hi, 0, 1, 2, 3, 4, 5, 6, 7);
    }
#pragma unroll
    for (int jj = 0; jj < 4; ++jj) {
      const i32x4 lo = *(const i32x4*)(bb + boff[jj]);
      const i32x4 hi = *(const i32x4*)(bb + (boff[jj] ^ 16));
      bv[jj] = __builtin_shufflevector(lo, hi, 0, 1, 2, 3, 4, 5, 6, 7);
    }
    __builtin_amdgcn_s_setprio(1);
#pragma unroll
    for (int i = 0; i < 4; ++i)
#pragma unroll
      for (int jj = 0; jj < 4; ++jj)
        acc[i][jj] = __builtin_amdgcn_mfma_scale_f32_16x16x128_f8f6f4(
            av[i], bv[jj], acc[i][jj], 0, 0, 0, SCALE1, 0, SCALE1);
    __builtin_amdgcn_s_setprio(0);
    asm volatile("s_waitcnt lgkmcnt(0)" ::: "memory");  // reads retired before overwrite
    __builtin_amdgcn_s_barrier();
  }

  // ---- epilogue: unscale + diag fixup + per-row (max, sumexp) base-2 partials ----
  const float ws2 = wp[0] * LOG2E;
  const float b2  = bp[0] * LOG2E;
  float2* red = (float2*)smem;  // 2KB in buf0's A region; last tile read buf1 -> safe

#pragma unroll
  for (int i = 0; i < 4; ++i) {
#pragma unroll
    for (int rr = 0; rr < 4; ++rr) {
      const int lrow = wr * 64 + i * 16 + lg * 4 + rr;  // 0..127
      const int R = rowbase + lrow;
      const int n = R / M_UTT;
      float l2[4];
#pragma unroll
      for (int jj = 0; jj < 4; ++jj) {
        float sim = acc[i][jj][rr] * INV_SS;
        const int gc = colbase + wc * 64 + jj * 16 + l16;
        if (gc == n) {
          sim = (40.f * sim - 1.f) * (1.f / 39.f);  // exclusive centroid; ||xn|| = 1
          picked2[R] = fmaf(ws2, sim, b2);
        }
        l2[jj] = fmaf(ws2, sim, b2);
      }
      float mx = fmaxf(fmaxf(l2[0], l2[1]), fmaxf(l2[2], l2[3]));
#pragma unroll
      for (int d = 1; d < 16; d <<= 1) mx = fmaxf(mx, __shfl_xor(mx, d, 64));
      float s = exp2f(l2[0] - mx) + exp2f(l2[1] - mx) +
                exp2f(l2[2] - mx) + exp2f(l2[3] - mx);
#pragma unroll
      for (int d = 1; d < 16; d <<= 1) s += __shfl_xor(s, d, 64);
      if (l16 == 0) red[lrow * 2 + wc] = make_float2(mx, s);
    }
  }
  __syncthreads();
  if (tid < 128) {
    const float2 p0 = red[tid * 2 + 0];
    const float2 p1 = red[tid * 2 + 1];
    const float m2 = fmaxf(p0.x, p1.x);
    const float ss = p0.y * exp2f(p0.x - m2) + p1.y * exp2f(p1.x - m2);
    ppart[(size_t)(rowbase + tid) * 8 + cb] = make_float2(m2, ss);
  }
}

// ---------------- Kernel 3: combine 8 col-block partials -> row loss ----------------
__global__ __launch_bounds__(256) void k_combine(const float2* __restrict__ pp,
                                                 const float* __restrict__ picked2,
                                                 float* __restrict__ rowloss) {
  const int R = blockIdx.x * 256 + threadIdx.x;
  const float2* p = pp + (size_t)R * 8;
  float2 v[8];
#pragma unroll
  for (int j = 0; j < 8; ++j) v[j] = p[j];
  float m2 = v[0].x;
#pragma unroll
  for (int j = 1; j < 8; ++j) m2 = fmaxf(m2, v[j].x);
  float s = 0.f;
#pragma unroll
  for (int j = 0; j < 8; ++j) s += v[j].y * exp2f(v[j].x - m2);
  const float lse2 = m2 + log2f(s);
  rowloss[R] = (lse2 - picked2[R]) * LN2;
}

// ---------------- Kernel 4: mean over all 40960 rows ----------------
__global__ __launch_bounds__(512) void k_reduce(const float* __restrict__ rowloss,
                                                float* __restrict__ out) {
  const int t = threadIdx.x;
  double s = 0.0;
  for (int i = t; i < NROWS; i += 512) s += (double)rowloss[i];
  __shared__ double sm[512];
  sm[t] = s;
  __syncthreads();
  for (int off = 256; off > 0; off >>= 1) {
    if (t < off) sm[t] += sm[t + off];
    __syncthreads();
  }
  if (t == 0) out[0] = (float)(sm[0] / (double)NROWS);
}

extern "C" void kernel_launch(void* const* d_in, const int* in_sizes, int n_in,
                              void* d_out, int out_size, void* d_ws, size_t ws_size,
                              hipStream_t stream) {
  const float* x = (const float*)d_in[0];
  const float* w = (const float*)d_in[1];
  const float* b = (const float*)d_in[2];
  char* ws = (char*)d_ws;
  size_t off = 0;
  unsigned char* xn = (unsigned char*)(ws + off); off += (size_t)NROWS * D_FEAT;
  unsigned char* cc = (unsigned char*)(ws + off); off += (size_t)N_SPK * D_FEAT;
  off = (off + 255) & ~(size_t)255;
  float2* ppart      = (float2*)(ws + off);        off += (size_t)NROWS * 8 * sizeof(float2);
  float* picked2     = (float*)(ws + off);         off += (size_t)NROWS * sizeof(float);
  float* rowloss     = (float*)(ws + off);         off += (size_t)NROWS * sizeof(float);
  float* out = (float*)d_out;

  k_norm_cent<<<N_SPK, 256, 0, stream>>>(x, xn, cc);
  k_gemm_part<<<(NROWS / BM) * (N_SPK / BN), 256, 0, stream>>>(xn, cc, w, b, ppart, picked2);
  k_combine<<<NROWS / 256, 256, 0, stream>>>(ppart, picked2, rowloss);
  k_reduce<<<1, 512, 0, stream>>>(rowloss, out);
}

// Round 11
// 305.197 us; speedup vs baseline: 1.0384x; 1.0384x over previous
//
#include <hip/hip_runtime.h>
#include <hip/hip_bf16.h>
#include <hip/hip_fp8.h>

typedef float f32x4 __attribute__((ext_vector_type(4)));
typedef int   i32x4 __attribute__((ext_vector_type(4)));
typedef int   i32x8 __attribute__((ext_vector_type(8)));

#define N_SPK 1024
#define M_UTT 40
#define D_FEAT 768
#define NROWS (N_SPK * M_UTT)
#define LOG2E 1.44269504088896340736f
#define LN2   0.69314718055994530942f

#define BM 128
#define BN 128
#define BKB 128            // fp8 elems (=bytes) per K-tile = one MX K-window
#define KT (D_FEAT / BKB)  // 6
#define ROWB 768           // bytes per fp8 source row

// xn stored *8, cc stored *8, scales = 1.0  ->  acc = 64 * sim
#define INV_SS (1.0f / 64.0f)
#define SCL 8.0f
#define SCALE1 0x7F7F7F7F  // e8m0 127 = 2^0 in all 4 bytes

__device__ __forceinline__ unsigned char to_fp8(float v) {
  __hip_fp8_e4m3 t(v);
  return (unsigned char)t.__x;
}

// Feature permutation (identical for xn and cc -> dot product invariant; within one
// MX 128-k window both operands present the same orig-k at the same byte position):
// within each 64-byte k-group, 16B slot m = orig k {8m..8m+7} ++ {32+8m..32+8m+7}.
// stored_j(j) = ((j>>3)&3)*16 + (j&7) + ((j>>5)<<3)

// ---------------- Kernel 1: fused L2-normalize + inclusive centroid (fp8, x8, permuted) ----------------
__global__ __launch_bounds__(256) void k_norm_cent(const float* __restrict__ x,
                                                   unsigned char* __restrict__ xn,
                                                   unsigned char* __restrict__ cc) {
  const int n = blockIdx.x, t = threadIdx.x;
  const float* xb = x + (size_t)n * (M_UTT * D_FEAT);
  unsigned char* ob = xn + (size_t)n * (M_UTT * D_FEAT);
  const int lane = t & 63, wv = t >> 6;
  const int j  = t & 63;
  const int pj = ((j >> 3) & 3) * 16 + (j & 7) + ((j >> 5) << 3);
  const int s0 = (t & ~63) + pj;
  __shared__ float wsum[2][2][4];  // [parity][row-in-pair][wave]
  float c0 = 0.f, c1 = 0.f, c2 = 0.f;
  for (int m = 0; m < M_UTT; m += 2) {
    const int p = (m >> 1) & 1;
    const float* r0 = xb + (size_t)m * D_FEAT;
    const float* r1 = r0 + D_FEAT;
    float a0 = r0[t], a1 = r0[t + 256], a2 = r0[t + 512];
    float b0 = r1[t], b1 = r1[t + 256], b2 = r1[t + 512];
    float sq0 = a0 * a0 + a1 * a1 + a2 * a2;
    float sq1 = b0 * b0 + b1 * b1 + b2 * b2;
#pragma unroll
    for (int d = 1; d < 64; d <<= 1) {
      sq0 += __shfl_xor(sq0, d, 64);
      sq1 += __shfl_xor(sq1, d, 64);
    }
    if (lane == 0) { wsum[p][0][wv] = sq0; wsum[p][1][wv] = sq1; }
    __syncthreads();  // parity double-buffer: slot p reused 2 barriers later -> safe
    const float t0 = wsum[p][0][0] + wsum[p][0][1] + wsum[p][0][2] + wsum[p][0][3];
    const float t1 = wsum[p][1][0] + wsum[p][1][1] + wsum[p][1][2] + wsum[p][1][3];
    const float i0 = 1.0f / fmaxf(sqrtf(t0), 1e-12f);
    const float i1 = 1.0f / fmaxf(sqrtf(t1), 1e-12f);
    a0 *= i0; a1 *= i0; a2 *= i0;
    b0 *= i1; b1 *= i1; b2 *= i1;
    unsigned char* o0 = ob + (size_t)m * D_FEAT;
    unsigned char* o1 = o0 + D_FEAT;
    o0[s0] = to_fp8(a0 * SCL); o0[s0 + 256] = to_fp8(a1 * SCL); o0[s0 + 512] = to_fp8(a2 * SCL);
    o1[s0] = to_fp8(b0 * SCL); o1[s0 + 256] = to_fp8(b1 * SCL); o1[s0 + 512] = to_fp8(b2 * SCL);
    c0 += a0 + b0; c1 += a1 + b1; c2 += a2 + b2;
  }
  unsigned char* co = cc + (size_t)n * D_FEAT;
  co[s0]       = to_fp8(c0 * (SCL / M_UTT));
  co[s0 + 256] = to_fp8(c1 * (SCL / M_UTT));
  co[s0 + 512] = to_fp8(c2 * (SCL / M_UTT));
}

// ---------------- Kernel 2: 128x128 MX-fp8 GEMM, K=128/tile, R8 LDS layout, 2 blocks/CU ----------------
// 256 thr = 4 waves (2x2 of 64x64; 4x4 frags of mfma_scale 16x16x128; 16 MFMA/K-tile).
// A K-tile = two R8-format 64-k sub-tiles per matrix. LDS buffer (32KB):
//   A-klo [0,8K) A-khi [8K,16K) B-klo [16K,24K) B-khi [24K,32K); dbuf = 64KB.
// Each sub-tile: 64 LDS-rows of 128B = 2 src rows pair-packed, phys = logical ^ ((R&7)<<4)
// (R8's verified 0-conflict scheme; GLD dest linear, source pre-swizzled).
// Lane (l16,lg): 32 operand bytes = slots 2*(lg&1), +1 of sub-tile (lg>>1) -> two
// ds_read_b128 at in0 and in0^16; per quarter-wave each 4-bank span hit exactly 2x (free).
// Register discipline (R10 spill fix): bv[4] (32 regs) per tile; av one i at a time.
// Loop: stage k+1 (8 GLD) -> vmcnt(8) -> barrier -> reads+MFMA -> lgkmcnt(0) -> barrier.
// Grid 2560 = exactly 5 generations of 512 resident blocks (2/CU) -> no tail.
#define GLD(g, l) __builtin_amdgcn_global_load_lds( \
    (const __attribute__((address_space(1))) unsigned int*)(g), \
    (__attribute__((address_space(3))) unsigned int*)(l), 16, 0, 0)

__global__ __launch_bounds__(256, 2) void k_gemm_part(
    const unsigned char* __restrict__ XN, const unsigned char* __restrict__ CC,
    const float* __restrict__ wp, const float* __restrict__ bp,
    float2* __restrict__ ppart, float* __restrict__ picked2) {

  __shared__ __align__(16) char smem[65536];

  const int tid  = threadIdx.x;
  const int wave = tid >> 6, lane = tid & 63;
  const int l16  = lane & 15, lg = lane >> 4;
  const int wr   = wave >> 1, wc = wave & 1;

  // XCD swizzle: 2560 = 8 XCD x 320; a row-tile's 8 col-blocks share one XCD's L2
  const int bid = blockIdx.x;
  const int xcd = bid & 7;
  const int tt  = bid >> 3;              // 0..319
  const int rb  = xcd * 40 + (tt >> 3);  // 0..319
  const int cb  = tt & 7;                // 0..7
  const int rowbase = rb * BM;
  const int colbase = cb * BN;

  // staging source mapping (R8 verbatim; repeats per 64B k-group):
  // thread t fills LDS bytes chunk*4096 + t*16; LDS-row R = o>>7,
  // logical_inner = (o&127) ^ ((R&7)<<4); src_row = 2R + (li>>6), src k-byte = li&63.
  const int R7   = (tid >> 3) & 7;
  const int li   = ((tid & 7) * 16) ^ (R7 << 4);
  const int row0 = 2 * (tid >> 3) + (li >> 6);   // 0..63
  const int kb   = li & 63;
  const int t16  = tid * 16;
  const unsigned char* gA = XN + (size_t)(rowbase + row0) * ROWB + kb;
  const unsigned char* gB = CC + (size_t)(colbase + row0) * ROWB + kb;

  // fragment reads: src row r = band*64 + i*16 + l16 -> LDS-row R = band*32 + i*8 + (l16>>1);
  // in0 = ((l16&1)<<6 | (lg&1)<<5) ^ ((l16>>1 & 7)<<4); pair read = in0, in0^16;
  // sub-tile select hsel = (lg>>1)*8192.
  const int xr   = ((l16 >> 1) & 7) << 4;
  const int in0  = (((l16 & 1) << 6) | ((lg & 1) << 5)) ^ xr;
  const int hsel = (lg >> 1) * 8192;
  int aoff[4], boff[4];
#pragma unroll
  for (int i = 0; i < 4; ++i) {
    aoff[i] = hsel + (wr * 32 + i * 8 + (l16 >> 1)) * 128 + in0;
    boff[i] = 16384 + hsel + (wc * 32 + i * 8 + (l16 >> 1)) * 128 + in0;
  }

  f32x4 acc[4][4];
#pragma unroll
  for (int i = 0; i < 4; ++i)
#pragma unroll
    for (int jj = 0; jj < 4; ++jj) acc[i][jj] = (f32x4){0.f, 0.f, 0.f, 0.f};

  auto STAGE = [&](int buf, int koff) {
    char* sb = smem + buf * 32768;
    GLD(gA + koff,                  sb + t16);            // A k-lo rows 0-63
    GLD(gA + 64 * ROWB + koff,      sb +  4096 + t16);    // A k-lo rows 64-127
    GLD(gA + koff + 64,             sb +  8192 + t16);    // A k-hi rows 0-63
    GLD(gA + 64 * ROWB + koff + 64, sb + 12288 + t16);    // A k-hi rows 64-127
    GLD(gB + koff,                  sb + 16384 + t16);
    GLD(gB + 64 * ROWB + koff,      sb + 20480 + t16);
    GLD(gB + koff + 64,             sb + 24576 + t16);
    GLD(gB + 64 * ROWB + koff + 64, sb + 28672 + t16);
  };

  STAGE(0, 0);  // prologue: tile 0

  for (int k = 0; k < KT; ++k) {
    const char* bb = smem + (k & 1) * 32768;
    if (k + 1 < KT) {
      STAGE((k + 1) & 1, (k + 1) * BKB);
      asm volatile("s_waitcnt vmcnt(8)" ::: "memory");  // tile k landed; k+1 in flight
    } else {
      asm volatile("s_waitcnt vmcnt(0)" ::: "memory");
    }
    __builtin_amdgcn_s_barrier();

    i32x8 bv[4];
#pragma unroll
    for (int jj = 0; jj < 4; ++jj) {
      const i32x4 lo = *(const i32x4*)(bb + boff[jj]);
      const i32x4 hi = *(const i32x4*)(bb + (boff[jj] ^ 16));
      bv[jj] = __builtin_shufflevector(lo, hi, 0, 1, 2, 3, 4, 5, 6, 7);
    }
    __builtin_amdgcn_s_setprio(1);
#pragma unroll
    for (int i = 0; i < 4; ++i) {
      const i32x4 alo = *(const i32x4*)(bb + aoff[i]);
      const i32x4 ahi = *(const i32x4*)(bb + (aoff[i] ^ 16));
      const i32x8 av = __builtin_shufflevector(alo, ahi, 0, 1, 2, 3, 4, 5, 6, 7);
#pragma unroll
      for (int jj = 0; jj < 4; ++jj)
        acc[i][jj] = __builtin_amdgcn_mfma_scale_f32_16x16x128_f8f6f4(
            av, bv[jj], acc[i][jj], 0, 0, 0, SCALE1, 0, SCALE1);
    }
    __builtin_amdgcn_s_setprio(0);
    asm volatile("s_waitcnt lgkmcnt(0)" ::: "memory");  // reads retired before overwrite
    __builtin_amdgcn_s_barrier();
  }

  // ---- epilogue: unscale + diag fixup + per-row (max, sumexp) base-2 partials ----
  const float ws2 = wp[0] * LOG2E;
  const float b2  = bp[0] * LOG2E;
  float2* red = (float2*)smem;  // 2KB in buf0's A region; last tile read buf1 -> safe

#pragma unroll
  for (int i = 0; i < 4; ++i) {
#pragma unroll
    for (int rr = 0; rr < 4; ++rr) {
      const int lrow = wr * 64 + i * 16 + lg * 4 + rr;  // 0..127
      const int R = rowbase + lrow;
      const int n = R / M_UTT;
      float l2[4];
#pragma unroll
      for (int jj = 0; jj < 4; ++jj) {
        float sim = acc[i][jj][rr] * INV_SS;
        const int gc = colbase + wc * 64 + jj * 16 + l16;
        if (gc == n) {
          sim = (40.f * sim - 1.f) * (1.f / 39.f);  // exclusive centroid; ||xn|| = 1
          picked2[R] = fmaf(ws2, sim, b2);
        }
        l2[jj] = fmaf(ws2, sim, b2);
      }
      float mx = fmaxf(fmaxf(l2[0], l2[1]), fmaxf(l2[2], l2[3]));
#pragma unroll
      for (int d = 1; d < 16; d <<= 1) mx = fmaxf(mx, __shfl_xor(mx, d, 64));
      float s = exp2f(l2[0] - mx) + exp2f(l2[1] - mx) +
                exp2f(l2[2] - mx) + exp2f(l2[3] - mx);
#pragma unroll
      for (int d = 1; d < 16; d <<= 1) s += __shfl_xor(s, d, 64);
      if (l16 == 0) red[lrow * 2 + wc] = make_float2(mx, s);
    }
  }
  __syncthreads();
  if (tid < 128) {
    const float2 p0 = red[tid * 2 + 0];
    const float2 p1 = red[tid * 2 + 1];
    const float m2 = fmaxf(p0.x, p1.x);
    const float ss = p0.y * exp2f(p0.x - m2) + p1.y * exp2f(p1.x - m2);
    ppart[(size_t)(rowbase + tid) * 8 + cb] = make_float2(m2, ss);
  }
}

// ---------------- Kernel 3: combine 8 col-block partials -> row loss ----------------
__global__ __launch_bounds__(256) void k_combine(const float2* __restrict__ pp,
                                                 const float* __restrict__ picked2,
                                                 float* __restrict__ rowloss) {
  const int R = blockIdx.x * 256 + threadIdx.x;
  const float2* p = pp + (size_t)R * 8;
  float2 v[8];
#pragma unroll
  for (int j = 0; j < 8; ++j) v[j] = p[j];
  float m2 = v[0].x;
#pragma unroll
  for (int j = 1; j < 8; ++j) m2 = fmaxf(m2, v[j].x);
  float s = 0.f;
#pragma unroll
  for (int j = 0; j < 8; ++j) s += v[j].y * exp2f(v[j].x - m2);
  const float lse2 = m2 + log2f(s);
  rowloss[R] = (lse2 - picked2[R]) * LN2;
}

// ---------------- Kernel 4: mean over all 40960 rows ----------------
__global__ __launch_bounds__(512) void k_reduce(const float* __restrict__ rowloss,
                                                float* __restrict__ out) {
  const int t = threadIdx.x;
  double s = 0.0;
  for (int i = t; i < NROWS; i += 512) s += (double)rowloss[i];
  __shared__ double sm[512];
  sm[t] = s;
  __syncthreads();
  for (int off = 256; off > 0; off >>= 1) {
    if (t < off) sm[t] += sm[t + off];
    __syncthreads();
  }
  if (t == 0) out[0] = (float)(sm[0] / (double)NROWS);
}

extern "C" void kernel_launch(void* const* d_in, const int* in_sizes, int n_in,
                              void* d_out, int out_size, void* d_ws, size_t ws_size,
                              hipStream_t stream) {
  const float* x = (const float*)d_in[0];
  const float* w = (const float*)d_in[1];
  const float* b = (const float*)d_in[2];
  char* ws = (char*)d_ws;
  size_t off = 0;
  unsigned char* xn = (unsigned char*)(ws + off); off += (size_t)NROWS * D_FEAT;
  unsigned char* cc = (unsigned char*)(ws + off); off += (size_t)N_SPK * D_FEAT;
  off = (off + 255) & ~(size_t)255;
  float2* ppart      = (float2*)(ws + off);        off += (size_t)NROWS * 8 * sizeof(float2);
  float* picked2     = (float*)(ws + off);         off += (size_t)NROWS * sizeof(float);
  float* rowloss     = (float*)(ws + off);         off += (size_t)NROWS * sizeof(float);
  float* out = (float*)d_out;

  k_norm_cent<<<N_SPK, 256, 0, stream>>>(x, xn, cc);
  k_gemm_part<<<(NROWS / BM) * (N_SPK / BN), 256, 0, stream>>>(xn, cc, w, b, ppart, picked2);
  k_combine<<<NROWS / 256, 256, 0, stream>>>(ppart, picked2, rowloss);
  k_reduce<<<1, 512, 0, stream>>>(rowloss, out);
}

// Round 12
// 123.919 us; speedup vs baseline: 2.5575x; 2.4629x over previous
//
#include <hip/hip_runtime.h>
#include <hip/hip_bf16.h>
#include <hip/hip_fp8.h>

typedef float f32x4 __attribute__((ext_vector_type(4)));
typedef long long i64;
typedef i64 i64x2 __attribute__((ext_vector_type(2)));

#define N_SPK 1024
#define M_UTT 40
#define D_FEAT 768
#define NROWS (N_SPK * M_UTT)
#define LOG2E 1.44269504088896340736f
#define LN2   0.69314718055994530942f

#define BM 128
#define BN 128
#define BKB 64             // fp8 elems (=bytes) per K-tile
#define KT (D_FEAT / BKB)  // 12
#define ROWB 768           // bytes per fp8 source row

// xn stored *8, cc stored *8  ->  acc = 64 * sim
#define INV_SS (1.0f / 64.0f)
#define SCL 8.0f

__device__ __forceinline__ unsigned char to_fp8(float v) {
  __hip_fp8_e4m3 t(v);
  return (unsigned char)t.__x;
}

// Feature permutation (identical for xn and cc -> dot product invariant):
// within each 64-byte k-group, 16B slot m = orig k {8m..8m+7} ++ {32+8m..32+8m+7},
// so ONE ds_read_b128 yields both MFMA k-substeps (lo = sub0, hi = sub1).
// stored_j(j) = ((j>>3)&3)*16 + (j&7) + ((j>>5)<<3)

// ---------------- Kernel 1: fused L2-normalize + inclusive centroid (fp8, x8, permuted) ----------------
__global__ __launch_bounds__(256) void k_norm_cent(const float* __restrict__ x,
                                                   unsigned char* __restrict__ xn,
                                                   unsigned char* __restrict__ cc) {
  const int n = blockIdx.x, t = threadIdx.x;
  const float* xb = x + (size_t)n * (M_UTT * D_FEAT);
  unsigned char* ob = xn + (size_t)n * (M_UTT * D_FEAT);
  const int lane = t & 63, wv = t >> 6;
  const int j  = t & 63;
  const int pj = ((j >> 3) & 3) * 16 + (j & 7) + ((j >> 5) << 3);
  const int s0 = (t & ~63) + pj;
  __shared__ float wsum[2][2][4];  // [parity][row-in-pair][wave]
  float c0 = 0.f, c1 = 0.f, c2 = 0.f;
  for (int m = 0; m < M_UTT; m += 2) {
    const int p = (m >> 1) & 1;
    const float* r0 = xb + (size_t)m * D_FEAT;
    const float* r1 = r0 + D_FEAT;
    float a0 = r0[t], a1 = r0[t + 256], a2 = r0[t + 512];
    float b0 = r1[t], b1 = r1[t + 256], b2 = r1[t + 512];
    float sq0 = a0 * a0 + a1 * a1 + a2 * a2;
    float sq1 = b0 * b0 + b1 * b1 + b2 * b2;
#pragma unroll
    for (int d = 1; d < 64; d <<= 1) {
      sq0 += __shfl_xor(sq0, d, 64);
      sq1 += __shfl_xor(sq1, d, 64);
    }
    if (lane == 0) { wsum[p][0][wv] = sq0; wsum[p][1][wv] = sq1; }
    __syncthreads();  // parity double-buffer: slot p reused 2 barriers later -> safe
    const float t0 = wsum[p][0][0] + wsum[p][0][1] + wsum[p][0][2] + wsum[p][0][3];
    const float t1 = wsum[p][1][0] + wsum[p][1][1] + wsum[p][1][2] + wsum[p][1][3];
    const float i0 = 1.0f / fmaxf(sqrtf(t0), 1e-12f);
    const float i1 = 1.0f / fmaxf(sqrtf(t1), 1e-12f);
    a0 *= i0; a1 *= i0; a2 *= i0;
    b0 *= i1; b1 *= i1; b2 *= i1;
    unsigned char* o0 = ob + (size_t)m * D_FEAT;
    unsigned char* o1 = o0 + D_FEAT;
    o0[s0] = to_fp8(a0 * SCL); o0[s0 + 256] = to_fp8(a1 * SCL); o0[s0 + 512] = to_fp8(a2 * SCL);
    o1[s0] = to_fp8(b0 * SCL); o1[s0 + 256] = to_fp8(b1 * SCL); o1[s0 + 512] = to_fp8(b2 * SCL);
    c0 += a0 + b0; c1 += a1 + b1; c2 += a2 + b2;
  }
  unsigned char* co = cc + (size_t)n * D_FEAT;
  co[s0]       = to_fp8(c0 * (SCL / M_UTT));
  co[s0 + 256] = to_fp8(c1 * (SCL / M_UTT));
  co[s0 + 512] = to_fp8(c2 * (SCL / M_UTT));
}

// ---------------- Kernel 2: 128x128 fp8 GEMM, 512 thr / 8 waves, 24 waves/CU ----------------
// 8 waves = 2 row-bands x 4 col-bands; wave-tile 64x32 -> acc = 4x2 frags = 32 regs/thread
// (halved vs R8's 64 so __launch_bounds__(512,6) [cap 85] fits with NO spill -> 3 blocks/CU
// = 24 waves/CU, 1.5x the TLP of R8's best; occupancy is the measured dominant knob:
// 8/12/16 waves/CU -> 152/108/88 us).
// LDS/staging/swizzle = R8 verbatim: 32KB dbuf, 64B src rows pair-packed into 128B LDS
// rows, phys = logical ^ ((R&7)<<4), GLD linear-dest + pre-swizzled source (0 conflicts),
// permuted-k so one ds_read_b128 feeds both k-substeps.
// Loop: stage k+1 (2 GLD) -> vmcnt(2) -> barrier -> 6 ds_read_b128 + 16 MFMA ->
// lgkmcnt(0) -> barrier. Never vmcnt(0) mid-loop.
#define GLD(g, l) __builtin_amdgcn_global_load_lds( \
    (const __attribute__((address_space(1))) unsigned int*)(g), \
    (__attribute__((address_space(3))) unsigned int*)(l), 16, 0, 0)

__global__ __launch_bounds__(512, 6) void k_gemm_part(
    const unsigned char* __restrict__ XN, const unsigned char* __restrict__ CC,
    const float* __restrict__ wp, const float* __restrict__ bp,
    float2* __restrict__ ppart, float* __restrict__ picked2) {

  __shared__ __align__(16) char smem[32768];

  const int tid  = threadIdx.x;
  const int wave = tid >> 6, lane = tid & 63;
  const int l16  = lane & 15, lg = lane >> 4;
  const int wr2  = wave >> 2;      // 0..1: row band (64 rows)
  const int wc4  = wave & 3;       // 0..3: col band (32 cols)

  // XCD swizzle: 2560 = 8 XCD x 320; a row-tile's 8 col-blocks share one XCD's L2
  const int bid = blockIdx.x;
  const int xcd = bid & 7;
  const int tt  = bid >> 3;              // 0..319
  const int rb  = xcd * 40 + (tt >> 3);  // 0..319
  const int cb  = tt & 7;                // 0..7
  const int rowbase = rb * BM;
  const int colbase = cb * BN;

  // staging (512 threads, 1 GLD per matrix per tile): thread t fills LDS bytes t*16;
  // LDS-row R = t>>3 (0..63); logical_inner = ((t&7)*16) ^ ((R&7)<<4);
  // src_row = 2R + (li>>6) in [0,128), src k-byte = li&63.
  const int R7   = (tid >> 3) & 7;
  const int li   = ((tid & 7) * 16) ^ (R7 << 4);
  const int row0 = 2 * (tid >> 3) + (li >> 6);   // 0..127
  const int kb   = li & 63;
  const int t16  = tid * 16;
  const unsigned char* gA = XN + (size_t)(rowbase + row0) * ROWB + kb;
  const unsigned char* gB = CC + (size_t)(colbase + row0) * ROWB + kb;

  // fragment ds_read_b128 offsets (R8 formula, re-banded):
  // A frag row = wr2*64 + i*16 + l16 -> LDS-row = wr2*32 + i*8 + (l16>>1)
  // B frag col = wc4*32 + j*16 + l16 -> LDS-row = wc4*16 + j*8 + (l16>>1)
  // inner logical = ((l16&1)<<6)|(lg<<4), phys = logical ^ (((l16>>1)&7)<<4)
  const int xr  = ((l16 >> 1) & 7) << 4;
  const int in0 = ((((l16 & 1) << 6) | (lg << 4)) ^ xr);
  int aoff[4], boff[2];
#pragma unroll
  for (int i = 0; i < 4; ++i)
    aoff[i] = (wr2 * 32 + i * 8 + (l16 >> 1)) * 128 + in0;
#pragma unroll
  for (int jj = 0; jj < 2; ++jj)
    boff[jj] = 8192 + (wc4 * 16 + jj * 8 + (l16 >> 1)) * 128 + in0;

  f32x4 acc[4][2];
#pragma unroll
  for (int i = 0; i < 4; ++i)
#pragma unroll
    for (int jj = 0; jj < 2; ++jj) acc[i][jj] = (f32x4){0.f, 0.f, 0.f, 0.f};

  auto STAGE = [&](int buf, int koff) {
    char* sb = smem + buf * 16384;
    GLD(gA + koff, sb + t16);           // A region [0,8K)
    GLD(gB + koff, sb + 8192 + t16);    // B region [8K,16K)
  };

  STAGE(0, 0);  // prologue: tile 0 (2 loads outstanding)

  for (int k = 0; k < KT; ++k) {
    const char* bb = smem + (k & 1) * 16384;
    if (k + 1 < KT) {
      STAGE((k + 1) & 1, (k + 1) * BKB);
      asm volatile("s_waitcnt vmcnt(2)" ::: "memory");  // tile k landed; k+1 in flight
    } else {
      asm volatile("s_waitcnt vmcnt(0)" ::: "memory");
    }
    __builtin_amdgcn_s_barrier();

    i64x2 bv[2];
#pragma unroll
    for (int jj = 0; jj < 2; ++jj) bv[jj] = *(const i64x2*)(bb + boff[jj]);
    __builtin_amdgcn_s_setprio(1);
#pragma unroll
    for (int i = 0; i < 4; ++i) {
      const i64x2 av = *(const i64x2*)(bb + aoff[i]);
#pragma unroll
      for (int jj = 0; jj < 2; ++jj) {
        acc[i][jj] = __builtin_amdgcn_mfma_f32_16x16x32_fp8_fp8(av[0], bv[jj][0], acc[i][jj], 0, 0, 0);
        acc[i][jj] = __builtin_amdgcn_mfma_f32_16x16x32_fp8_fp8(av[1], bv[jj][1], acc[i][jj], 0, 0, 0);
      }
    }
    __builtin_amdgcn_s_setprio(0);
    asm volatile("s_waitcnt lgkmcnt(0)" ::: "memory");  // reads retired before overwrite
    __builtin_amdgcn_s_barrier();
  }

  // ---- epilogue: unscale + diag fixup + per-row (max, sumexp) base-2 partials ----
  const float ws2 = wp[0] * LOG2E;
  const float b2  = bp[0] * LOG2E;
  float2* red = (float2*)smem;  // [128][4] float2 = 4KB, safe after final barrier

#pragma unroll
  for (int i = 0; i < 4; ++i) {
#pragma unroll
    for (int rr = 0; rr < 4; ++rr) {
      const int lrow = wr2 * 64 + i * 16 + lg * 4 + rr;  // 0..127
      const int R = rowbase + lrow;
      const int n = R / M_UTT;
      float l2[2];
#pragma unroll
      for (int jj = 0; jj < 2; ++jj) {
        float sim = acc[i][jj][rr] * INV_SS;
        const int gc = colbase + wc4 * 32 + jj * 16 + l16;
        if (gc == n) {
          sim = (40.f * sim - 1.f) * (1.f / 39.f);  // exclusive centroid; ||xn|| = 1
          picked2[R] = fmaf(ws2, sim, b2);
        }
        l2[jj] = fmaf(ws2, sim, b2);
      }
      float mx = fmaxf(l2[0], l2[1]);
#pragma unroll
      for (int d = 1; d < 16; d <<= 1) mx = fmaxf(mx, __shfl_xor(mx, d, 64));
      float s = exp2f(l2[0] - mx) + exp2f(l2[1] - mx);
#pragma unroll
      for (int d = 1; d < 16; d <<= 1) s += __shfl_xor(s, d, 64);
      if (l16 == 0) red[lrow * 4 + wc4] = make_float2(mx, s);
    }
  }
  __syncthreads();
  if (tid < 128) {
    const float2 v0 = red[tid * 4 + 0];
    const float2 v1 = red[tid * 4 + 1];
    const float2 v2 = red[tid * 4 + 2];
    const float2 v3 = red[tid * 4 + 3];
    const float m2 = fmaxf(fmaxf(v0.x, v1.x), fmaxf(v2.x, v3.x));
    const float ss = v0.y * exp2f(v0.x - m2) + v1.y * exp2f(v1.x - m2) +
                     v2.y * exp2f(v2.x - m2) + v3.y * exp2f(v3.x - m2);
    ppart[(size_t)(rowbase + tid) * 8 + cb] = make_float2(m2, ss);
  }
}

// ---------------- Kernel 3: combine 8 col-block partials -> row loss ----------------
__global__ __launch_bounds__(256) void k_combine(const float2* __restrict__ pp,
                                                 const float* __restrict__ picked2,
                                                 float* __restrict__ rowloss) {
  const int R = blockIdx.x * 256 + threadIdx.x;
  const float2* p = pp + (size_t)R * 8;
  float2 v[8];
#pragma unroll
  for (int j = 0; j < 8; ++j) v[j] = p[j];
  float m2 = v[0].x;
#pragma unroll
  for (int j = 1; j < 8; ++j) m2 = fmaxf(m2, v[j].x);
  float s = 0.f;
#pragma unroll
  for (int j = 0; j < 8; ++j) s += v[j].y * exp2f(v[j].x - m2);
  const float lse2 = m2 + log2f(s);
  rowloss[R] = (lse2 - picked2[R]) * LN2;
}

// ---------------- Kernel 4: mean over all 40960 rows ----------------
__global__ __launch_bounds__(512) void k_reduce(const float* __restrict__ rowloss,
                                                float* __restrict__ out) {
  const int t = threadIdx.x;
  double s = 0.0;
  for (int i = t; i < NROWS; i += 512) s += (double)rowloss[i];
  __shared__ double sm[512];
  sm[t] = s;
  __syncthreads();
  for (int off = 256; off > 0; off >>= 1) {
    if (t < off) sm[t] += sm[t + off];
    __syncthreads();
  }
  if (t == 0) out[0] = (float)(sm[0] / (double)NROWS);
}

extern "C" void kernel_launch(void* const* d_in, const int* in_sizes, int n_in,
                              void* d_out, int out_size, void* d_ws, size_t ws_size,
                              hipStream_t stream) {
  const float* x = (const float*)d_in[0];
  const float* w = (const float*)d_in[1];
  const float* b = (const float*)d_in[2];
  char* ws = (char*)d_ws;
  size_t off = 0;
  unsigned char* xn = (unsigned char*)(ws + off); off += (size_t)NROWS * D_FEAT;
  unsigned char* cc = (unsigned char*)(ws + off); off += (size_t)N_SPK * D_FEAT;
  off = (off + 255) & ~(size_t)255;
  float2* ppart      = (float2*)(ws + off);        off += (size_t)NROWS * 8 * sizeof(float2);
  float* picked2     = (float*)(ws + off);         off += (size_t)NROWS * sizeof(float);
  float* rowloss     = (float*)(ws + off);         off += (size_t)NROWS * sizeof(float);
  float* out = (float*)d_out;

  k_norm_cent<<<N_SPK, 256, 0, stream>>>(x, xn, cc);
  k_gemm_part<<<(NROWS / BM) * (N_SPK / BN), 512, 0, stream>>>(xn, cc, w, b, ppart, picked2);
  k_combine<<<NROWS / 256, 256, 0, stream>>>(ppart, picked2, rowloss);
  k_reduce<<<1, 512, 0, stream>>>(rowloss, out);
}

// Round 14
// 95.055 us; speedup vs baseline: 3.3341x; 1.3037x over previous
//
#include <hip/hip_runtime.h>
#include <hip/hip_bf16.h>
#include <hip/hip_fp8.h>

typedef float f32x4 __attribute__((ext_vector_type(4)));
typedef long long i64;
typedef i64 i64x2 __attribute__((ext_vector_type(2)));

#define N_SPK 1024
#define M_UTT 40
#define D_FEAT 768
#define NROWS (N_SPK * M_UTT)
#define LOG2E 1.44269504088896340736f
#define LN2   0.69314718055994530942f

#define BM 128
#define BN 128
#define BKB 64             // fp8 elems (=bytes) per K-tile
#define KT (D_FEAT / BKB)  // 12
#define ROWB 768           // bytes per fp8 source row

// xn stored *8, cc stored *8  ->  acc = 64 * sim
#define INV_SS (1.0f / 64.0f)
#define SCL 8.0f

__device__ __forceinline__ unsigned char to_fp8(float v) {
  __hip_fp8_e4m3 t(v);
  return (unsigned char)t.__x;
}

// Feature permutation (identical for xn and cc -> dot product invariant):
// within each 64-byte k-group, 16B slot m = orig k {8m..8m+7} ++ {32+8m..32+8m+7},
// so ONE ds_read_b128 yields both MFMA k-substeps (lo = sub0, hi = sub1).
// stored_j(j) = ((j>>3)&3)*16 + (j&7) + ((j>>5)<<3
// For a 4-aligned k base b (b%4==0) the 4 bytes b..b+3 stay CONSECUTIVE after the
// permutation (only j&7 varies, contiguously) -> uchar4 stores are valid.
__device__ __forceinline__ int perm4base(int k0) {  // k0 % 4 == 0
  const int b = k0 & 63;
  return (k0 & ~63) + ((b >> 3) & 3) * 16 + (b & 7) + ((b >> 5) << 3);
}

// ---------------- Kernel 1: fused L2-normalize + centroid, float4 loads (G13) ----------------
// 256 thr, one speaker; 4 rows per group (10 groups). Flat float4 index f = q*256 + t
// (q=0..2) over the 4-row span: row o = f/192 is WAVE-UNIFORM (boundaries at multiples
// of 64). Wave-contrib idx = 4q+wv -> row (4q+wv)/3, slot (4q+wv)%3 (3 waves per row).
// Centroid partials: (o = f/192, c4 = f%192) is a bijection over 4x192 slots ->
// direct LDS stores, no zero-init, no atomics.
__global__ __launch_bounds__(256) void k_norm_cent(const float* __restrict__ x,
                                                   unsigned char* __restrict__ xn,
                                                   unsigned char* __restrict__ cc) {
  const int n = blockIdx.x, t = threadIdx.x;
  const int lane = t & 63, wv = t >> 6;
  const float4* xb4 = (const float4*)(x + (size_t)n * (M_UTT * D_FEAT));
  unsigned char* ob = xn + (size_t)n * (M_UTT * D_FEAT);

  __shared__ float bins[2][4][3];    // [parity][row][slot]
  __shared__ float cl[4][192][4];    // 12KB: [owner][col4][comp]

  int o_[3], c4_[3], soff_[3];
#pragma unroll
  for (int q = 0; q < 3; ++q) {
    const int f = q * 256 + t;
    o_[q]  = f / 192;
    c4_[q] = f % 192;
    soff_[q] = perm4base(4 * c4_[q]);
  }

  float cacc[3][4];
#pragma unroll
  for (int q = 0; q < 3; ++q)
#pragma unroll
    for (int c = 0; c < 4; ++c) cacc[q][c] = 0.f;

  for (int g = 0; g < M_UTT / 4; ++g) {
    const int p = g & 1;
    float4 v[3];
#pragma unroll
    for (int q = 0; q < 3; ++q) v[q] = xb4[g * 768 + q * 256 + t];
    float ss[3];
#pragma unroll
    for (int q = 0; q < 3; ++q)
      ss[q] = v[q].x * v[q].x + v[q].y * v[q].y + v[q].z * v[q].z + v[q].w * v[q].w;
#pragma unroll
    for (int d = 1; d < 64; d <<= 1) {
      ss[0] += __shfl_xor(ss[0], d, 64);
      ss[1] += __shfl_xor(ss[1], d, 64);
      ss[2] += __shfl_xor(ss[2], d, 64);
    }
    if (lane == 0) {
#pragma unroll
      for (int q = 0; q < 3; ++q) {
        const int idx = 4 * q + wv;
        bins[p][idx / 3][idx % 3] = ss[q];
      }
    }
    __syncthreads();  // parity dbuf: bins[p] rewritten 2 syncs later -> safe
#pragma unroll
    for (int q = 0; q < 3; ++q) {
      const int o = o_[q];
      const float tot = bins[p][o][0] + bins[p][o][1] + bins[p][o][2];
      const float iv = 1.0f / fmaxf(sqrtf(tot), 1e-12f);
      const float w0 = v[q].x * iv, w1 = v[q].y * iv, w2 = v[q].z * iv, w3 = v[q].w * iv;
      cacc[q][0] += w0; cacc[q][1] += w1; cacc[q][2] += w2; cacc[q][3] += w3;
      uchar4 u;
      u.x = to_fp8(w0 * SCL); u.y = to_fp8(w1 * SCL);
      u.z = to_fp8(w2 * SCL); u.w = to_fp8(w3 * SCL);
      *(uchar4*)(ob + (size_t)(4 * g + o) * D_FEAT + soff_[q]) = u;
    }
  }

  // centroid merge: direct injective stores, then 192 threads finalize
#pragma unroll
  for (int q = 0; q < 3; ++q) {
#pragma unroll
    for (int c = 0; c < 4; ++c) cl[o_[q]][c4_[q]][c] = cacc[q][c];
  }
  __syncthreads();
  if (t < 192) {
    float s[4];
#pragma unroll
    for (int c = 0; c < 4; ++c)
      s[c] = cl[0][t][c] + cl[1][t][c] + cl[2][t][c] + cl[3][t][c];
    const float sc = SCL / (float)M_UTT;
    uchar4 u;
    u.x = to_fp8(s[0] * sc); u.y = to_fp8(s[1] * sc);
    u.z = to_fp8(s[2] * sc); u.w = to_fp8(s[3] * sc);
    *(uchar4*)(cc + (size_t)n * D_FEAT + perm4base(4 * t)) = u;
  }
}

// ---------------- Kernel 2: 128x128 fp8 GEMM (verified R8 kernel, verbatim) ----------------
// 256 thr = 4 waves (2x2 of 64x64; 4x4 frags of 16x16x32 fp8; 32 MFMA per K-tile).
// LDS 32KB dbuf (16KB/tile): 64B src rows pair-packed into 128B LDS rows, XOR swizzle
// physical_inner = logical ^ ((R&7)<<4). Frag read = ONE ds_read_b128 per (frag,row)
// (permuted k-layout packs both substeps) -- measured 0 bank conflicts.
// Loop: stage k+1 -> vmcnt(4) -> barrier -> 8x ds_read_b128 + 32 MFMA -> lgkmcnt(0)
// -> barrier. Never vmcnt(0) mid-loop. launch_bounds(256,4): cap 128 >= 64 acc + ~50.
#define GLD(g, l) __builtin_amdgcn_global_load_lds( \
    (const __attribute__((address_space(1))) unsigned int*)(g), \
    (__attribute__((address_space(3))) unsigned int*)(l), 16, 0, 0)

__global__ __launch_bounds__(256, 4) void k_gemm_part(
    const unsigned char* __restrict__ XN, const unsigned char* __restrict__ CC,
    const float* __restrict__ wp, const float* __restrict__ bp,
    float2* __restrict__ ppart, float* __restrict__ picked2) {

  __shared__ __align__(16) char smem[32768];

  const int tid  = threadIdx.x;
  const int wave = tid >> 6, lane = tid & 63;
  const int l16  = lane & 15, lg = lane >> 4;
  const int wr   = wave >> 1, wc = wave & 1;

  // XCD swizzle: 2560 = 8 XCD x 320; a row-tile's 8 col-blocks share one XCD's L2
  const int bid = blockIdx.x;
  const int xcd = bid & 7;
  const int tt  = bid >> 3;              // 0..319
  const int rb  = xcd * 40 + (tt >> 3);  // 0..319
  const int cb  = tt & 7;                // 0..7
  const int rowbase = rb * BM;
  const int colbase = cb * BN;

  // staging source mapping (inverse of pair-packed swizzle):
  // thread t fills LDS bytes o = chunk*4096 + t*16; LDS-row R = o>>7,
  // logical_inner = (o&127) ^ ((R&7)<<4); src_row = 2R + (li>>6), src k-byte = li&63.
  const int R7   = (tid >> 3) & 7;
  const int li   = ((tid & 7) * 16) ^ (R7 << 4);
  const int row0 = 2 * (tid >> 3) + (li >> 6);   // 0..63
  const int kb   = li & 63;
  const int t16  = tid * 16;
  const unsigned char* gA = XN + (size_t)(rowbase + row0) * ROWB + kb;
  const unsigned char* gB = CC + (size_t)(colbase + row0) * ROWB + kb;

  // fragment ds_read_b128 offsets: src row r = band*64 + i*16 + l16 ->
  // LDS-row R = band*32 + i*8 + (l16>>1); logical inner = ((l16&1)<<6)|(lg<<4),
  // physical = logical ^ ((R&7)<<4)
  const int xr  = ((l16 >> 1) & 7) << 4;
  const int in0 = ((((l16 & 1) << 6) | (lg << 4)) ^ xr);
  int aoff[4], boff[4];
#pragma unroll
  for (int i = 0; i < 4; ++i) {
    aoff[i] = (wr * 32 + i * 8 + (l16 >> 1)) * 128 + in0;
    boff[i] = 8192 + (wc * 32 + i * 8 + (l16 >> 1)) * 128 + in0;
  }

  f32x4 acc[4][4];
#pragma unroll
  for (int i = 0; i < 4; ++i)
#pragma unroll
    for (int jj = 0; jj < 4; ++jj) acc[i][jj] = (f32x4){0.f, 0.f, 0.f, 0.f};

  auto STAGE = [&](int buf, int koff) {
    char* sb = smem + buf * 16384;
    GLD(gA + koff,              sb + t16);
    GLD(gA + 64 * ROWB + koff,  sb + 4096 + t16);
    GLD(gB + koff,              sb + 8192 + t16);
    GLD(gB + 64 * ROWB + koff,  sb + 12288 + t16);
  };

  STAGE(0, 0);  // prologue: tile 0

  for (int k = 0; k < KT; ++k) {
    const char* bb = smem + (k & 1) * 16384;
    if (k + 1 < KT) {
      STAGE((k + 1) & 1, (k + 1) * BKB);
      asm volatile("s_waitcnt vmcnt(4)" ::: "memory");  // tile k landed; k+1 in flight
    } else {
      asm volatile("s_waitcnt vmcnt(0)" ::: "memory");
    }
    __builtin_amdgcn_s_barrier();

    i64x2 av[4], bv[4];
#pragma unroll
    for (int i = 0; i < 4; ++i) av[i] = *(const i64x2*)(bb + aoff[i]);
#pragma unroll
    for (int jj = 0; jj < 4; ++jj) bv[jj] = *(const i64x2*)(bb + boff[jj]);
    __builtin_amdgcn_s_setprio(1);
#pragma unroll
    for (int i = 0; i < 4; ++i)
#pragma unroll
      for (int jj = 0; jj < 4; ++jj)
        acc[i][jj] = __builtin_amdgcn_mfma_f32_16x16x32_fp8_fp8(av[i][0], bv[jj][0], acc[i][jj], 0, 0, 0);
#pragma unroll
    for (int i = 0; i < 4; ++i)
#pragma unroll
      for (int jj = 0; jj < 4; ++jj)
        acc[i][jj] = __builtin_amdgcn_mfma_f32_16x16x32_fp8_fp8(av[i][1], bv[jj][1], acc[i][jj], 0, 0, 0);
    __builtin_amdgcn_s_setprio(0);
    asm volatile("s_waitcnt lgkmcnt(0)" ::: "memory");  // reads retired before overwrite
    __builtin_amdgcn_s_barrier();
  }

  // ---- epilogue: unscale + diag fixup + per-row (max, sumexp) base-2 partials ----
  const float ws2 = wp[0] * LOG2E;
  const float b2  = bp[0] * LOG2E;
  float2* red = (float2*)smem;  // [128][2] float2 = 2KB, safe after final barrier

#pragma unroll
  for (int i = 0; i < 4; ++i) {
#pragma unroll
    for (int rr = 0; rr < 4; ++rr) {
      const int lrow = wr * 64 + i * 16 + lg * 4 + rr;  // 0..127
      const int R = rowbase + lrow;
      const int n = R / M_UTT;
      float l2[4];
#pragma unroll
      for (int jj = 0; jj < 4; ++jj) {
        float sim = acc[i][jj][rr] * INV_SS;
        const int gc = colbase + wc * 64 + jj * 16 + l16;
        if (gc == n) {
          sim = (40.f * sim - 1.f) * (1.f / 39.f);  // exclusive centroid; ||xn|| = 1
          picked2[R] = fmaf(ws2, sim, b2);
        }
        l2[jj] = fmaf(ws2, sim, b2);
      }
      float mx = fmaxf(fmaxf(l2[0], l2[1]), fmaxf(l2[2], l2[3]));
#pragma unroll
      for (int d = 1; d < 16; d <<= 1) mx = fmaxf(mx, __shfl_xor(mx, d, 64));
      float s = exp2f(l2[0] - mx) + exp2f(l2[1] - mx) +
                exp2f(l2[2] - mx) + exp2f(l2[3] - mx);
#pragma unroll
      for (int d = 1; d < 16; d <<= 1) s += __shfl_xor(s, d, 64);
      if (l16 == 0) red[lrow * 2 + wc] = make_float2(mx, s);
    }
  }
  __syncthreads();
  if (tid < 128) {
    const float2 p0 = red[tid * 2 + 0];
    const float2 p1 = red[tid * 2 + 1];
    const float m2 = fmaxf(p0.x, p1.x);
    const float ss = p0.y * exp2f(p0.x - m2) + p1.y * exp2f(p1.x - m2);
    ppart[(size_t)(rowbase + tid) * 8 + cb] = make_float2(m2, ss);
  }
}

// ---------------- Kernel 3: combine partials -> row loss + per-block sum ----------------
__global__ __launch_bounds__(256) void k_combine(const float2* __restrict__ pp,
                                                 const float* __restrict__ picked2,
                                                 double* __restrict__ partial) {
  const int t = threadIdx.x;
  const int R = blockIdx.x * 256 + t;
  const float2* p = pp + (size_t)R * 8;
  float2 v[8];
#pragma unroll
  for (int j = 0; j < 8; ++j) v[j] = p[j];
  float m2 = v[0].x;
#pragma unroll
  for (int j = 1; j < 8; ++j) m2 = fmaxf(m2, v[j].x);
  float s = 0.f;
#pragma unroll
  for (int j = 0; j < 8; ++j) s += v[j].y * exp2f(v[j].x - m2);
  const float lse2 = m2 + log2f(s);
  const float rl = (lse2 - picked2[R]) * LN2;

  __shared__ double sm[256];
  sm[t] = (double)rl;
  __syncthreads();
  for (int off = 128; off > 0; off >>= 1) {
    if (t < off) sm[t] += sm[t + off];
    __syncthreads();
  }
  if (t == 0) partial[blockIdx.x] = sm[0];
}

// ---------------- Kernel 4: final mean over 160 block partials ----------------
__global__ __launch_bounds__(256) void k_reduce(const double* __restrict__ partial,
                                                float* __restrict__ out) {
  const int t = threadIdx.x;
  __shared__ double sm[256];
  sm[t] = (t < NROWS / 256) ? partial[t] : 0.0;
  __syncthreads();
  for (int off = 128; off > 0; off >>= 1) {
    if (t < off) sm[t] += sm[t + off];
    __syncthreads();
  }
  if (t == 0) out[0] = (float)(sm[0] / (double)NROWS);
}

extern "C" void kernel_launch(void* const* d_in, const int* in_sizes, int n_in,
                              void* d_out, int out_size, void* d_ws, size_t ws_size,
                              hipStream_t stream) {
  const float* x = (const float*)d_in[0];
  const float* w = (const float*)d_in[1];
  const float* b = (const float*)d_in[2];
  char* ws = (char*)d_ws;
  size_t off = 0;
  unsigned char* xn = (unsigned char*)(ws + off); off += (size_t)NROWS * D_FEAT;
  unsigned char* cc = (unsigned char*)(ws + off); off += (size_t)N_SPK * D_FEAT;
  off = (off + 255) & ~(size_t)255;
  float2* ppart   = (float2*)(ws + off); off += (size_t)NROWS * 8 * sizeof(float2);
  float* picked2  = (float*)(ws + off);  off += (size_t)NROWS * sizeof(float);
  off = (off + 255) & ~(size_t)255;
  double* partial = (double*)(ws + off); off += (size_t)(NROWS / 256) * sizeof(double);
  float* out = (float*)d_out;

  k_norm_cent<<<N_SPK, 256, 0, stream>>>(x, xn, cc);
  k_gemm_part<<<(NROWS / BM) * (N_SPK / BN), 256, 0, stream>>>(xn, cc, w, b, ppart, picked2);
  k_combine<<<NROWS / 256, 256, 0, stream>>>(ppart, picked2, partial);
  k_reduce<<<1, 256, 0, stream>>>(partial, out);
}